// Round 11
// baseline (1073.886 us; speedup 1.0000x reference)
//
#include <hip/hip_runtime.h>
#include <hip/hip_bf16.h>

// Problem constants
#define NB 64      // batch
#define NT_ 64     // time steps
#define NS 512     // source positions
#define NI 512     // input dim
#define NH 512     // hidden
#define G4 2048    // 4*H
#define H2 1024    // 2*H
#define BT (NB*NT_)
#define RBLK 64    // persistent-kernel blocks
#define CPB 8      // cells per block
#define WROW 528   // padded LDS row for Whh slices (528 bf16 = 1056 B) -> 2-way banks

typedef __attribute__((ext_vector_type(8))) short short8;   // 8 bf16 (4 VGPRs)
typedef __attribute__((ext_vector_type(4))) float f32x4;    // MFMA accumulator

__device__ __forceinline__ short f2bs(float f) {
    __hip_bfloat16 h = __float2bfloat16(f);
    return *reinterpret_cast<short*>(&h);
}
__device__ __forceinline__ float bs2f(short s) {
    unsigned int u = ((unsigned int)(unsigned short)s) << 16;
    union { unsigned int u; float f; } c; c.u = u; return c.f;
}
__device__ __forceinline__ short8 ld8b(const __hip_bfloat16* p) {
    return *reinterpret_cast<const short8*>(p);
}
__device__ __forceinline__ short8 mk8(unsigned long long a, unsigned long long b) {
    union { unsigned long long q[2]; short8 s; } u;
    u.q[0] = a; u.q[1] = b;
    return u.s;
}
// a 4B word is valid iff != 0xFFFFFFFF (two bf16 NaNs — unreachable from finite h/lo)
__device__ __forceinline__ bool okq(unsigned long long q) {
    return ((unsigned)q != 0xFFFFFFFFu) && ((unsigned)(q >> 32) != 0xFFFFFFFFu);
}
// load 8 fp32, produce hi & lo bf16 fragments (x ~= hi + lo, rel err ~2^-16)
__device__ __forceinline__ void ld8f2(const float* p, short8& hi, short8& lo) {
    float4 a = *reinterpret_cast<const float4*>(p);
    float4 b = *reinterpret_cast<const float4*>(p + 4);
    float v[8] = {a.x,a.y,a.z,a.w,b.x,b.y,b.z,b.w};
    #pragma unroll
    for (int i = 0; i < 8; i++) {
        short h = f2bs(v[i]);
        hi[i] = h;
        lo[i] = f2bs(v[i] - bs2f(h));
    }
}
__device__ __forceinline__ float fsigm(float x){ return 1.f/(1.f + __expf(-x)); }
__device__ __forceinline__ float ftanh(float x){ float e = __expf(2.f*x); return 1.f - 2.f/(e + 1.f); }

// ---------------- conversions ----------------
__global__ __launch_bounds__(256) void conv_split(const float* __restrict__ s,
                                                  __hip_bfloat16* __restrict__ hi,
                                                  __hip_bfloat16* __restrict__ lo, int n) {
    for (int i = blockIdx.x*256 + threadIdx.x; i < n; i += gridDim.x*256) {
        float x = s[i];
        __hip_bfloat16 h = __float2bfloat16(x);
        hi[i] = h;
        lo[i] = __float2bfloat16(x - __bfloat162float(h));
    }
}

// hs region init — ALL writes are device-scope relaxed atomic u32 stores
// (write-through: no dirty L2 copies that could later evict and stomp L3 over
// the recurrence's produced values — the r7 NaN mechanism).
// slot 0 <- packed h0 hi/lo; slots 1..64 <- 0xFFFFFFFF sentinel.
__global__ __launch_bounds__(256) void hseq0_init(const float* __restrict__ h0,
                                                  __hip_bfloat16* __restrict__ hs_h,
                                                  __hip_bfloat16* __restrict__ hs_l) {
    int i = blockIdx.x*256 + threadIdx.x;
    const int nsent = NB*NH*NT_/2;     // u32 words in slots 1..64 (per array)
    unsigned* ph = (unsigned*)(hs_h + NB*NH);
    unsigned* pl = (unsigned*)(hs_l + NB*NH);
    for (int k = i; k < nsent; k += gridDim.x*256) {
        __hip_atomic_store(&ph[k], 0xFFFFFFFFu, __ATOMIC_RELAXED, __HIP_MEMORY_SCOPE_AGENT);
        __hip_atomic_store(&pl[k], 0xFFFFFFFFu, __ATOMIC_RELAXED, __HIP_MEMORY_SCOPE_AGENT);
    }
    if (i < NB*NH/2) {
        float v0 = h0[2*i], v1 = h0[2*i+1];
        unsigned short h0b = (unsigned short)f2bs(v0);
        unsigned short h1b = (unsigned short)f2bs(v1);
        unsigned short l0b = (unsigned short)f2bs(v0 - bs2f((short)h0b));
        unsigned short l1b = (unsigned short)f2bs(v1 - bs2f((short)h1b));
        __hip_atomic_store((unsigned*)hs_h + i, (unsigned)h0b | ((unsigned)h1b << 16),
                           __ATOMIC_RELAXED, __HIP_MEMORY_SCOPE_AGENT);
        __hip_atomic_store((unsigned*)hs_l + i, (unsigned)l0b | ((unsigned)l1b << 16),
                           __ATOMIC_RELAXED, __HIP_MEMORY_SCOPE_AGENT);
    }
}

// ctxT[b][h][s] = bf16(ctx[s][b][h])  — for the wc GEMM (dot over s)
__global__ __launch_bounds__(256) void transpose_ctx(const float* __restrict__ ctx,
                                                     __hip_bfloat16* __restrict__ ctxT) {
    __shared__ float tile[64][65];
    int s0 = blockIdx.x*64, h0 = blockIdx.y*64, b = blockIdx.z;
    int tx = threadIdx.x & 63, ty = threadIdx.x >> 6;
    for (int i = 0; i < 16; i++) {
        int s = i*4 + ty;
        tile[s][tx] = ctx[(size_t)(s0+s)*NB*NH + (size_t)b*NH + h0 + tx];
    }
    __syncthreads();
    for (int i = 0; i < 16; i++) {
        int h = i*4 + ty;
        ctxT[(size_t)b*NH*NS + (size_t)(h0+h)*NS + s0 + tx] = __float2bfloat16(tile[tx][h]);
    }
}

// ---------------- XW = input @ W_ih^T + b_ih + b_hh  (M=4096,N=2048,K=512) ----------------
__global__ __launch_bounds__(256) void gemm_xw(const __hip_bfloat16* __restrict__ Xh,
                                               const __hip_bfloat16* __restrict__ Xl,
                                               const __hip_bfloat16* __restrict__ Wh,
                                               const __hip_bfloat16* __restrict__ Wl,
                                               const float* __restrict__ b_ih,
                                               const float* __restrict__ b_hh,
                                               float* __restrict__ XW) {
    int wid = blockIdx.x*4 + (threadIdx.x>>6);
    int lane = threadIdx.x & 63;
    int m0 = (wid >> 5) * 64;
    int n0 = (wid & 31) * 64;
    int fr = lane & 15, fq = lane >> 4;
    f32x4 acc[4][4] = {};
    for (int kk = 0; kk < NI; kk += 32) {
        short8 ah[4], al[4], bh[4], bl[4];
        #pragma unroll
        for (int i = 0; i < 4; i++) {
            size_t off = (size_t)(m0+i*16+fr)*NI + kk + fq*8;
            ah[i] = ld8b(Xh + off);
            al[i] = ld8b(Xl + off);
        }
        #pragma unroll
        for (int j = 0; j < 4; j++) {
            bh[j] = ld8b(Wh + (size_t)(n0+j*16+fr)*NI + kk + fq*8);
            bl[j] = ld8b(Wl + (size_t)(n0+j*16+fr)*NI + kk + fq*8);
        }
        #pragma unroll
        for (int i = 0; i < 4; i++)
            #pragma unroll
            for (int j = 0; j < 4; j++) {
                acc[i][j] = __builtin_amdgcn_mfma_f32_16x16x32_bf16(ah[i], bh[j], acc[i][j], 0,0,0);
                acc[i][j] = __builtin_amdgcn_mfma_f32_16x16x32_bf16(ah[i], bl[j], acc[i][j], 0,0,0);
                acc[i][j] = __builtin_amdgcn_mfma_f32_16x16x32_bf16(al[i], bh[j], acc[i][j], 0,0,0);
            }
    }
    #pragma unroll
    for (int i = 0; i < 4; i++)
      #pragma unroll
      for (int j = 0; j < 4; j++)
        #pragma unroll
        for (int r = 0; r < 4; r++) {
            int m = m0 + i*16 + fq*4 + r;
            int n = n0 + j*16 + fr;
            XW[(size_t)m*G4 + n] = acc[i][j][r] + b_ih[n] + b_hh[n];
        }
}

// ---------------- persistent LSTM recurrence: pure dataflow, NO grid barrier ----------------
// (r8's kernel — forensics: r8 produced the same hs as the proven r6 kernel; its
// failure was the tail overlay, now removed.)
// 64 blocks x 256 threads. Block bi owns cells [bi*8, bi*8+8) -> 32 gate columns.
// Whh slice (hi+lo) in LDS (1056B padded rows, 2-way banks). c-state in registers.
//   - EVERY write to hs is a device-scope relaxed atomic u32 store (write-through,
//     no dirty L2 copies anywhere).
//   - readers poll THE DATA with device-scope relaxed u64 atomic loads against the
//     0xFFFF sentinel; polled values ARE the MFMA operands. Producer never waits.
//   - intra-block: gl double-buffered by t parity; ONE raw s_barrier per step
//     (lgkmcnt-only drain — no vmem drain anywhere in the loop).
__global__ __launch_bounds__(256, 1) void lstm_persist(
    const float* __restrict__ c0,
    const __hip_bfloat16* __restrict__ Whh_h,
    const __hip_bfloat16* __restrict__ Whh_l,
    const float* __restrict__ XW,
    __hip_bfloat16* __restrict__ hs_h,   // (65,B,H) bf16 time-series
    __hip_bfloat16* __restrict__ hs_l,
    float* __restrict__ hT, float* __restrict__ cT)
{
    __shared__ __hip_bfloat16 Wh[32*WROW];  // 33 KB, padded rows
    __shared__ __hip_bfloat16 Wl[32*WROW];  // 33 KB
    __shared__ float gl[2][4][32][33];      // double-buffered per-wave partials (33.8 KB)
    int tid = threadIdx.x, bi = blockIdx.x;
    int lane = tid & 63, w = tid >> 6;
    int fr = lane & 15, fq = lane >> 4;

    // --- stage Whh slice into LDS (row jl: gate jl>>3, cell bi*8+(jl&7)) ---
    {
        int jl = tid >> 3, ck8 = tid & 7;
        int grow = (jl >> 3) * NH + bi * CPB + (jl & 7);
        const short8* srcH = (const short8*)(Whh_h + (size_t)grow * NH);
        const short8* srcL = (const short8*)(Whh_l + (size_t)grow * NH);
        #pragma unroll
        for (int cc = 0; cc < 8; cc++) {
            int ck = ck8 * 8 + cc;                       // 16B chunk 0..63
            *(short8*)((char*)Wh + jl*(WROW*2) + ck*16) = srcH[ck];
            *(short8*)((char*)Wl + jl*(WROW*2) + ck*16) = srcL[ck];
        }
    }
    // --- c-state in registers: thread -> (batch eb, cells ec0..ec0+1) ---
    int eb  = tid >> 2;
    int ec0 = (tid & 3) * 2;
    int ebl = eb & 31, mhalf = eb >> 5;
    float creg[2];
    creg[0] = c0[eb * NH + bi*CPB + ec0];
    creg[1] = c0[eb * NH + bi*CPB + ec0 + 1];
    // XW for t=0
    float xw[8];
    #pragma unroll
    for (int g = 0; g < 4; g++)
      #pragma unroll
      for (int u = 0; u < 2; u++)
        xw[g*2+u] = XW[(size_t)eb*NT_*G4 + g*NH + bi*CPB + ec0 + u];
    __syncthreads();

    int m0 = (w & 1) * 32;      // M-half (batch rows)
    int kbase = (w >> 1) * 256; // K-half

    for (int t = 0; t < NT_; t++) {
        int p = t & 1;

        // --- data-poll + load the wave's A quadrant (hi+lo), 64 x u64 ---
        unsigned long long qa[2][8][2], ql[2][8][2];
        {
            const char* bH0 = (const char*)(hs_h + (size_t)t*NB*NH + (size_t)(m0+fr)*NH + kbase);
            const char* bL0 = (const char*)(hs_l + (size_t)t*NB*NH + (size_t)(m0+fr)*NH + kbase);
            const char* bH1 = bH0 + 16*NH*2;
            const char* bL1 = bL0 + 16*NH*2;
            int guard = 0; bool ok;
            do {
                ok = true;
                #pragma unroll
                for (int i = 0; i < 2; i++) {
                    const char* bH = i ? bH1 : bH0;
                    const char* bL = i ? bL1 : bL0;
                    #pragma unroll
                    for (int k8 = 0; k8 < 8; k8++) {
                        unsigned long long* pH = (unsigned long long*)(bH + k8*64 + fq*16);
                        unsigned long long* pL = (unsigned long long*)(bL + k8*64 + fq*16);
                        qa[i][k8][0] = __hip_atomic_load(pH,   __ATOMIC_RELAXED, __HIP_MEMORY_SCOPE_AGENT);
                        qa[i][k8][1] = __hip_atomic_load(pH+1, __ATOMIC_RELAXED, __HIP_MEMORY_SCOPE_AGENT);
                        ql[i][k8][0] = __hip_atomic_load(pL,   __ATOMIC_RELAXED, __HIP_MEMORY_SCOPE_AGENT);
                        ql[i][k8][1] = __hip_atomic_load(pL+1, __ATOMIC_RELAXED, __HIP_MEMORY_SCOPE_AGENT);
                    }
                }
                #pragma unroll
                for (int i = 0; i < 2; i++)
                  #pragma unroll
                  for (int k8 = 0; k8 < 8; k8++)
                    ok = ok && okq(qa[i][k8][0]) && okq(qa[i][k8][1])
                            && okq(ql[i][k8][0]) && okq(ql[i][k8][1]);
                if (!__all(ok)) __builtin_amdgcn_s_sleep(1);
            } while (!__all(ok) && ++guard < (1<<22));   // guard: fail loud, not hang
        }

        // --- split-GEMM on the polled registers ---
        f32x4 acc[2][2] = {};
        #pragma unroll
        for (int k8 = 0; k8 < 8; k8++) {
            short8 b_h[2], b_l[2];
            #pragma unroll
            for (int j = 0; j < 2; j++) {
                int jl = j*16 + fr;
                int byt = jl*(WROW*2) + (kbase + k8*32 + fq*8)*2;
                b_h[j] = *(const short8*)((const char*)Wh + byt);
                b_l[j] = *(const short8*)((const char*)Wl + byt);
            }
            #pragma unroll
            for (int i = 0; i < 2; i++) {
                short8 a_h = mk8(qa[i][k8][0], qa[i][k8][1]);
                short8 a_l = mk8(ql[i][k8][0], ql[i][k8][1]);
                #pragma unroll
                for (int j = 0; j < 2; j++) {
                    acc[i][j] = __builtin_amdgcn_mfma_f32_16x16x32_bf16(a_h, b_h[j], acc[i][j], 0,0,0);
                    acc[i][j] = __builtin_amdgcn_mfma_f32_16x16x32_bf16(a_h, b_l[j], acc[i][j], 0,0,0);
                    acc[i][j] = __builtin_amdgcn_mfma_f32_16x16x32_bf16(a_l, b_h[j], acc[i][j], 0,0,0);
                }
            }
        }
        #pragma unroll
        for (int i = 0; i < 2; i++)
          #pragma unroll
          for (int j = 0; j < 2; j++)
            #pragma unroll
            for (int r = 0; r < 4; r++)
                gl[p][w][i*16 + fq*4 + r][j*16 + fr] = acc[i][j][r];

        // --- ONE raw barrier: LDS drain only, vmem keeps flowing ---
        __builtin_amdgcn_sched_barrier(0);
        asm volatile("s_waitcnt lgkmcnt(0)" ::: "memory");
        __builtin_amdgcn_s_barrier();
        __builtin_amdgcn_sched_barrier(0);

        // --- cell elementwise (2 cells/thread): sum K-halves + XW, activate ---
        float hv[2];
        #pragma unroll
        for (int u = 0; u < 2; u++) {
            int cl = ec0 + u;
            float gi = gl[p][mhalf][ebl][cl]      + gl[p][2+mhalf][ebl][cl]      + xw[u];
            float gf = gl[p][mhalf][ebl][8 + cl]  + gl[p][2+mhalf][ebl][8 + cl]  + xw[2+u];
            float gg = gl[p][mhalf][ebl][16 + cl] + gl[p][2+mhalf][ebl][16 + cl] + xw[4+u];
            float go = gl[p][mhalf][ebl][24 + cl] + gl[p][2+mhalf][ebl][24 + cl] + xw[6+u];
            float ct = fsigm(gf)*creg[u] + fsigm(gi)*ftanh(gg);
            hv[u] = fsigm(go)*ftanh(ct);
            creg[u] = ct;
        }
        int hcol = bi*CPB + ec0;
        size_t hoff = (size_t)(t+1)*NB*NH + (size_t)eb*NH + hcol;
        unsigned short h0b = (unsigned short)f2bs(hv[0]);
        unsigned short h1b = (unsigned short)f2bs(hv[1]);
        unsigned ph = (unsigned)h0b | ((unsigned)h1b << 16);
        unsigned short l0b = (unsigned short)f2bs(hv[0] - bs2f((short)h0b));
        unsigned short l1b = (unsigned short)f2bs(hv[1] - bs2f((short)h1b));
        unsigned pl = (unsigned)l0b | ((unsigned)l1b << 16);
        __hip_atomic_store((unsigned*)&hs_h[hoff], ph, __ATOMIC_RELAXED, __HIP_MEMORY_SCOPE_AGENT);
        __hip_atomic_store((unsigned*)&hs_l[hoff], pl, __ATOMIC_RELAXED, __HIP_MEMORY_SCOPE_AGENT);
        if (t == NT_-1) {
            *(float2*)&hT[(size_t)eb*NH + hcol] = make_float2(hv[0], hv[1]);
            *(float2*)&cT[(size_t)eb*NH + hcol] = make_float2(creg[0], creg[1]);
        }
        // prefetch next step's XW (plain loads; consumed next cell phase)
        if (t + 1 < NT_) {
            #pragma unroll
            for (int g = 0; g < 4; g++)
              #pragma unroll
              for (int u = 0; u < 2; u++)
                xw[g*2+u] = XW[((size_t)eb*NT_ + (t+1))*G4 + g*NH + bi*CPB + ec0 + u];
        }
        // no trailing barrier: gl is double-buffered; the next step's single
        // barrier orders buffer reuse (all waves' cell reads drained there).
    }
}

// ---------------- scores[b,t,s] = h[b,t,:] . ctx[s,b,:]  (A from hs hi/lo) ----------------
__global__ __launch_bounds__(256) void gemm_scores(const __hip_bfloat16* __restrict__ hs_h,
                                                   const __hip_bfloat16* __restrict__ hs_l,
                                                   const float* __restrict__ ctx,
                                                   float* __restrict__ scores) {
    int wid = blockIdx.x*4 + (threadIdx.x>>6);
    int lane = threadIdx.x & 63;
    int b  = wid >> 3;
    int n0 = (wid & 7) * 64;
    int fr = lane & 15, fq = lane >> 4;
    const __hip_bfloat16* Abh = hs_h + NB*NH + (size_t)b*NH;   // slot t+1, row stride NB*NH
    const __hip_bfloat16* Abl = hs_l + NB*NH + (size_t)b*NH;
    const float* Bb = ctx + (size_t)b*NH;
    f32x4 acc[4][4] = {};
    for (int kk = 0; kk < NH; kk += 32) {
        short8 ah[4], al[4], bh[4], bl[4];
        #pragma unroll
        for (int i = 0; i < 4; i++) {
            size_t off = (size_t)(i*16+fr)*NB*NH + kk + fq*8;
            ah[i] = ld8b(Abh + off);
            al[i] = ld8b(Abl + off);
        }
        #pragma unroll
        for (int j = 0; j < 4; j++) ld8f2(Bb + (size_t)(n0+j*16+fr)*NB*NH + kk + fq*8, bh[j], bl[j]);
        #pragma unroll
        for (int i = 0; i < 4; i++)
            #pragma unroll
            for (int j = 0; j < 4; j++) {
                acc[i][j] = __builtin_amdgcn_mfma_f32_16x16x32_bf16(ah[i], bh[j], acc[i][j], 0,0,0);
                acc[i][j] = __builtin_amdgcn_mfma_f32_16x16x32_bf16(ah[i], bl[j], acc[i][j], 0,0,0);
                acc[i][j] = __builtin_amdgcn_mfma_f32_16x16x32_bf16(al[i], bh[j], acc[i][j], 0,0,0);
            }
    }
    #pragma unroll
    for (int i = 0; i < 4; i++)
      #pragma unroll
      for (int j = 0; j < 4; j++)
        #pragma unroll
        for (int r = 0; r < 4; r++) {
            int t = i*16 + fq*4 + r;
            int s = n0 + j*16 + fr;
            scores[((size_t)b*NT_ + t)*NS + s] = acc[i][j][r];
        }
}

// ---------------- row softmax over S, output attn hi/lo bf16 ----------------
__global__ __launch_bounds__(256) void softmax_rows(const float* __restrict__ scores,
                                                    __hip_bfloat16* __restrict__ ah,
                                                    __hip_bfloat16* __restrict__ al) {
    int row = blockIdx.x*4 + (threadIdx.x>>6);
    int lane = threadIdx.x & 63;
    const float* r = scores + (size_t)row*NS;
    float v[8], mx = -1e30f;
    #pragma unroll
    for (int i = 0; i < 8; i++) { v[i] = r[lane + i*64]; mx = fmaxf(mx, v[i]); }
    #pragma unroll
    for (int off = 32; off; off >>= 1) mx = fmaxf(mx, __shfl_xor(mx, off));
    float sum = 0.f;
    #pragma unroll
    for (int i = 0; i < 8; i++) { v[i] = __expf(v[i]-mx); sum += v[i]; }
    #pragma unroll
    for (int off = 32; off; off >>= 1) sum += __shfl_xor(sum, off);
    float inv = 1.f/sum;
    #pragma unroll
    for (int i = 0; i < 8; i++) {
        float a = v[i]*inv;
        __hip_bfloat16 h = __float2bfloat16(a);
        ah[(size_t)row*NS + lane + i*64] = h;
        al[(size_t)row*NS + lane + i*64] = __float2bfloat16(a - __bfloat162float(h));
    }
}

// ---------------- Wc[b,t,h] = sum_s attn[b,t,s]*ctxT[b,h,s]  (fp32 out) ----------------
__global__ __launch_bounds__(256) void gemm_wc(const __hip_bfloat16* __restrict__ Ah,
                                               const __hip_bfloat16* __restrict__ Al,
                                               const __hip_bfloat16* __restrict__ ctxT,
                                               float* __restrict__ Wc) {
    int wid = blockIdx.x*4 + (threadIdx.x>>6);
    int lane = threadIdx.x & 63;
    int b  = wid >> 3;
    int n0 = (wid & 7) * 64;
    int fr = lane & 15, fq = lane >> 4;
    const __hip_bfloat16* Abh = Ah + (size_t)b*NT_*NS;
    const __hip_bfloat16* Abl = Al + (size_t)b*NT_*NS;
    const __hip_bfloat16* Bb  = ctxT + (size_t)b*NH*NS;
    f32x4 acc[4][4] = {};
    for (int kk = 0; kk < NS; kk += 32) {
        short8 ah[4], al[4], bb[4];
        #pragma unroll
        for (int i = 0; i < 4; i++) {
            ah[i] = ld8b(Abh + (size_t)(i*16+fr)*NS + kk + fq*8);
            al[i] = ld8b(Abl + (size_t)(i*16+fr)*NS + kk + fq*8);
        }
        #pragma unroll
        for (int j = 0; j < 4; j++) bb[j] = ld8b(Bb + (size_t)(n0+j*16+fr)*NS + kk + fq*8);
        #pragma unroll
        for (int i = 0; i < 4; i++)
            #pragma unroll
            for (int j = 0; j < 4; j++) {
                acc[i][j] = __builtin_amdgcn_mfma_f32_16x16x32_bf16(ah[i], bb[j], acc[i][j], 0,0,0);
                acc[i][j] = __builtin_amdgcn_mfma_f32_16x16x32_bf16(al[i], bb[j], acc[i][j], 0,0,0);
            }
    }
    #pragma unroll
    for (int i = 0; i < 4; i++)
      #pragma unroll
      for (int j = 0; j < 4; j++)
        #pragma unroll
        for (int r = 0; r < 4; r++) {
            int t = i*16 + fq*4 + r;
            int h = n0 + j*16 + fr;
            Wc[((size_t)b*NT_ + t)*NH + h] = acc[i][j][r];
        }
}

// ---------------- out = tanh([Wc|h] @ W_out^T)  (M=4096,N=512,K=1024) ----------------
__global__ __launch_bounds__(256) void gemm_out(const float* __restrict__ Wc,
                                                const __hip_bfloat16* __restrict__ hs_h,
                                                const __hip_bfloat16* __restrict__ hs_l,
                                                const __hip_bfloat16* __restrict__ Wh,
                                                const __hip_bfloat16* __restrict__ Wl,
                                                float* __restrict__ out) {
    int wid = blockIdx.x*4 + (threadIdx.x>>6);
    int lane = threadIdx.x & 63;
    int m0 = (wid >> 3) * 64;
    int n0 = (wid & 7) * 64;
    int fr = lane & 15, fq = lane >> 4;
    f32x4 acc[4][4] = {};
    // half 0: Wc (fp32, split on the fly), K cols [0,512)
    for (int kk = 0; kk < NH; kk += 32) {
        short8 ah[4], al[4], bh[4], bl[4];
        #pragma unroll
        for (int i = 0; i < 4; i++) ld8f2(Wc + (size_t)(m0+i*16+fr)*NH + kk + fq*8, ah[i], al[i]);
        #pragma unroll
        for (int j = 0; j < 4; j++) {
            bh[j] = ld8b(Wh + (size_t)(n0+j*16+fr)*H2 + kk + fq*8);
            bl[j] = ld8b(Wl + (size_t)(n0+j*16+fr)*H2 + kk + fq*8);
        }
        #pragma unroll
        for (int i = 0; i < 4; i++)
            #pragma unroll
            for (int j = 0; j < 4; j++) {
                acc[i][j] = __builtin_amdgcn_mfma_f32_16x16x32_bf16(ah[i], bh[j], acc[i][j], 0,0,0);
                acc[i][j] = __builtin_amdgcn_mfma_f32_16x16x32_bf16(ah[i], bl[j], acc[i][j], 0,0,0);
                acc[i][j] = __builtin_amdgcn_mfma_f32_16x16x32_bf16(al[i], bh[j], acc[i][j], 0,0,0);
            }
    }
    // half 1: h from hs time-series (bf16 hi/lo), K cols [512,1024)
    {
        const __hip_bfloat16* A2h = hs_h + NB*NH + (size_t)(m0>>6)*NH;  // row rloc=t -> slot t+1
        const __hip_bfloat16* A2l = hs_l + NB*NH + (size_t)(m0>>6)*NH;
        for (int kk = 0; kk < NH; kk += 32) {
            short8 ah[4], al[4], bh[4], bl[4];
            #pragma unroll
            for (int i = 0; i < 4; i++) {
                size_t off = (size_t)(i*16+fr)*NB*NH + kk + fq*8;
                ah[i] = ld8b(A2h + off);
                al[i] = ld8b(A2l + off);
            }
            #pragma unroll
            for (int j = 0; j < 4; j++) {
                bh[j] = ld8b(Wh + (size_t)(n0+j*16+fr)*H2 + NH + kk + fq*8);
                bl[j] = ld8b(Wl + (size_t)(n0+j*16+fr)*H2 + NH + kk + fq*8);
            }
            #pragma unroll
            for (int i = 0; i < 4; i++)
                #pragma unroll
                for (int j = 0; j < 4; j++) {
                    acc[i][j] = __builtin_amdgcn_mfma_f32_16x16x32_bf16(ah[i], bh[j], acc[i][j], 0,0,0);
                    acc[i][j] = __builtin_amdgcn_mfma_f32_16x16x32_bf16(ah[i], bl[j], acc[i][j], 0,0,0);
                    acc[i][j] = __builtin_amdgcn_mfma_f32_16x16x32_bf16(al[i], bh[j], acc[i][j], 0,0,0);
                }
        }
    }
    #pragma unroll
    for (int i = 0; i < 4; i++)
      #pragma unroll
      for (int j = 0; j < 4; j++)
        #pragma unroll
        for (int r = 0; r < 4; r++) {
            int m = m0 + i*16 + fq*4 + r;
            int n = n0 + j*16 + fr;
            out[(size_t)m*NH + n] = ftanh(acc[i][j][r]);
        }
}

// ---------------- workspace layout: see authoritative offsets in kernel_launch ----------------
// XW @0 (33.5MB, live gemm_xw->recurrence); scores/attn overlay @0 after recurrence.
// hs_h/hs_l (65,B,H) @33.5MB — persists through tail GEMMs. flags region unused.
// Xh/Xl bf16 (B,T,I) overlay the Wc region (dead until gemm_wc). Weights, ctxT after.
// NOTE (r9 post-mortem): a pre-split ctx_b (B,S,H) hi/lo tail needs 32MB+32MB and
// does NOT fit any dead region — r7-r9 failures were cbh/cbl (budgeted 16MB each)
// overrunning into hs. Do not reintroduce without a real 64MB home.

extern "C" void kernel_launch(void* const* d_in, const int* in_sizes, int n_in,
                              void* d_out, int out_size, void* d_ws, size_t ws_size,
                              hipStream_t stream) {
    const float* input = (const float*)d_in[0];
    const float* h0    = (const float*)d_in[1];
    const float* c0    = (const float*)d_in[2];
    const float* ctx   = (const float*)d_in[3];
    const float* W_ih  = (const float*)d_in[4];
    const float* b_ih  = (const float*)d_in[5];
    const float* W_hh  = (const float*)d_in[6];
    const float* b_hh  = (const float*)d_in[7];
    const float* W_out = (const float*)d_in[8];
    float* out = (float*)d_out;

    // authoritative offsets (bytes)
    const size_t OFF_XW     = 0;          // 33,554,432
    const size_t OFF_SCORES = 0;          //  8,388,608 (after recurrence)
    const size_t OFF_ATTN_H = 8388608;    //  4,194,304
    const size_t OFF_ATTN_L = 12582912;   //  4,194,304
    const size_t OFF_HS_H   = 33554432;   //  4,259,840 (65,B,H) — persists through tail
    const size_t OFF_HS_L   = 37814272;   //  4,259,840
    const size_t OFF_WC     = 42082304;   //  8,388,608  [Xh/Xl overlay pre-recurrence]
    const size_t OFF_XH     = 42082304;   //  4,194,304
    const size_t OFF_XL     = 46276608;   //  4,194,304
    const size_t OFF_WIH_H  = 50470912;   //  2,097,152
    const size_t OFF_WIH_L  = 52568064;   //  2,097,152
    const size_t OFF_WHH_H  = 54665216;   //  2,097,152
    const size_t OFF_WHH_L  = 56762368;   //  2,097,152
    const size_t OFF_WOUT_H = 58859520;   //  1,048,576
    const size_t OFF_WOUT_L = 59908096;   //  1,048,576
    const size_t OFF_CTXT   = 60956672;   // 33,554,432 -> end 94,511,104
    if (ws_size < 94511104u) return;  // fail loudly (d_out stays poisoned)

    char* ws = (char*)d_ws;
    float*          XW     = (float*)(ws + OFF_XW);
    float*          scores = (float*)(ws + OFF_SCORES);
    __hip_bfloat16* attn_h = (__hip_bfloat16*)(ws + OFF_ATTN_H);
    __hip_bfloat16* attn_l = (__hip_bfloat16*)(ws + OFF_ATTN_L);
    __hip_bfloat16* hs_h   = (__hip_bfloat16*)(ws + OFF_HS_H);
    __hip_bfloat16* hs_l   = (__hip_bfloat16*)(ws + OFF_HS_L);
    float*          Wc     = (float*)(ws + OFF_WC);
    __hip_bfloat16* Xh     = (__hip_bfloat16*)(ws + OFF_XH);
    __hip_bfloat16* Xl     = (__hip_bfloat16*)(ws + OFF_XL);
    __hip_bfloat16* Wih_h  = (__hip_bfloat16*)(ws + OFF_WIH_H);
    __hip_bfloat16* Wih_l  = (__hip_bfloat16*)(ws + OFF_WIH_L);
    __hip_bfloat16* Whh_h  = (__hip_bfloat16*)(ws + OFF_WHH_H);
    __hip_bfloat16* Whh_l  = (__hip_bfloat16*)(ws + OFF_WHH_L);
    __hip_bfloat16* Wout_h = (__hip_bfloat16*)(ws + OFF_WOUT_H);
    __hip_bfloat16* Wout_l = (__hip_bfloat16*)(ws + OFF_WOUT_L);
    __hip_bfloat16* ctxT   = (__hip_bfloat16*)(ws + OFF_CTXT);

    conv_split<<<2048, 256, 0, stream>>>(W_ih, Wih_h, Wih_l, G4*NI);
    conv_split<<<2048, 256, 0, stream>>>(W_hh, Whh_h, Whh_l, G4*NH);
    conv_split<<<1024, 256, 0, stream>>>(W_out, Wout_h, Wout_l, NH*H2);
    conv_split<<<2048, 256, 0, stream>>>(input, Xh, Xl, BT*NI);
    hseq0_init<<<128, 256, 0, stream>>>(h0, hs_h, hs_l);
    gemm_xw<<<512, 256, 0, stream>>>(Xh, Xl, Wih_h, Wih_l, b_ih, b_hh, XW);

    float* hT = out + (size_t)BT*NH;
    float* cT = hT + NB*NH;
    lstm_persist<<<RBLK, 256, 0, stream>>>(c0, Whh_h, Whh_l, XW, hs_h, hs_l, hT, cT);

    transpose_ctx<<<dim3(8,8,64), 256, 0, stream>>>(ctx, ctxT);
    gemm_scores<<<128, 256, 0, stream>>>(hs_h, hs_l, ctx, scores);
    softmax_rows<<<1024, 256, 0, stream>>>(scores, attn_h, attn_l);
    gemm_wc<<<128, 256, 0, stream>>>(attn_h, attn_l, ctxT, Wc);
    gemm_out<<<128, 256, 0, stream>>>(Wc, hs_h, hs_l, Wout_h, Wout_l, out);
}

// Round 12
// 635.579 us; speedup vs baseline: 1.6896x; 1.6896x over previous
//
#include <hip/hip_runtime.h>
#include <hip/hip_bf16.h>

// Problem constants
#define NB 64      // batch
#define NT_ 64     // time steps
#define NS 512     // source positions
#define NI 512     // input dim
#define NH 512     // hidden
#define G4 2048    // 4*H
#define H2 1024    // 2*H
#define BT (NB*NT_)
#define RBLK 64    // recurrence blocks
#define CPB 8      // cells per block
// mega-kernel role ranges
#define XWB 512    // gemm_xw blocks (64 t x 8 n-groups)
#define TRB 4096   // transpose blocks (8 s x 8 h x 64 b)
#define WOB 128    // W_out conv blocks
#define GRID_MEGA (RBLK + XWB + TRB + WOB)

typedef __attribute__((ext_vector_type(8))) short short8;   // 8 bf16 (4 VGPRs)
typedef __attribute__((ext_vector_type(4))) float f32x4;    // MFMA accumulator

__device__ __forceinline__ short f2bs(float f) {
    __hip_bfloat16 h = __float2bfloat16(f);
    return *reinterpret_cast<short*>(&h);
}
__device__ __forceinline__ float bs2f(short s) {
    unsigned int u = ((unsigned int)(unsigned short)s) << 16;
    union { unsigned int u; float f; } c; c.u = u; return c.f;
}
__device__ __forceinline__ short8 ld8b(const __hip_bfloat16* p) {
    return *reinterpret_cast<const short8*>(p);
}
// load 8 fp32, produce hi & lo bf16 fragments (x ~= hi + lo, rel err ~2^-16)
__device__ __forceinline__ void ld8f2(const float* p, short8& hi, short8& lo) {
    float4 a = *reinterpret_cast<const float4*>(p);
    float4 b = *reinterpret_cast<const float4*>(p + 4);
    float v[8] = {a.x,a.y,a.z,a.w,b.x,b.y,b.z,b.w};
    #pragma unroll
    for (int i = 0; i < 8; i++) {
        short h = f2bs(v[i]);
        hi[i] = h;
        lo[i] = f2bs(v[i] - bs2f(h));
    }
}
__device__ __forceinline__ float fsigm(float x){ return 1.f/(1.f + __expf(-x)); }
__device__ __forceinline__ float ftanh(float x){ float e = __expf(2.f*x); return 1.f - 2.f/(e + 1.f); }

// ---------------- conversions ----------------
__global__ __launch_bounds__(256) void conv_split(const float* __restrict__ s,
                                                  __hip_bfloat16* __restrict__ hi,
                                                  __hip_bfloat16* __restrict__ lo, int n) {
    for (int i = blockIdx.x*256 + threadIdx.x; i < n; i += gridDim.x*256) {
        float x = s[i];
        __hip_bfloat16 h = __float2bfloat16(x);
        hi[i] = h;
        lo[i] = __float2bfloat16(x - __bfloat162float(h));
    }
}

// h0 -> hs slot 0 (hi/lo); zero flags (64 x stride16 u32) + xwcnt (64 x stride16 u32)
__global__ __launch_bounds__(256) void hseq0_init(const float* __restrict__ h0,
                                                  __hip_bfloat16* __restrict__ hs_h,
                                                  __hip_bfloat16* __restrict__ hs_l,
                                                  unsigned* __restrict__ sync) {
    int i = blockIdx.x*256 + threadIdx.x;
    if (i < 2048) sync[i] = 0u;      // flags[0..1023] + xwcnt[1024..2047]
    if (i < NB*NH) {
        float x = h0[i];
        __hip_bfloat16 h = __float2bfloat16(x);
        hs_h[i] = h;
        hs_l[i] = __float2bfloat16(x - __bfloat162float(h));
    }
}

// =====================================================================================
// MEGA KERNEL: blocks 0-63 recurrence | 64-575 gemm_xw | 576-4671 transpose | rest Wout
// LDS union (83KB) -> 1 block/CU for all roles.
// =====================================================================================
__global__ __launch_bounds__(256, 1) void lstm_mega(
    const float* __restrict__ c0,
    const __hip_bfloat16* __restrict__ Whh_h,
    const __hip_bfloat16* __restrict__ Whh_l,
    const __hip_bfloat16* __restrict__ Xh,
    const __hip_bfloat16* __restrict__ Xl,
    const __hip_bfloat16* __restrict__ Wih_h,
    const __hip_bfloat16* __restrict__ Wih_l,
    const float* __restrict__ b_ih,
    const float* __restrict__ b_hh,
    float* __restrict__ XW2,             // (T,B,4H) fp32, t-major
    __hip_bfloat16* __restrict__ hs_h,   // (65,B,H) bf16 time-series
    __hip_bfloat16* __restrict__ hs_l,
    float* __restrict__ hT, float* __restrict__ cT,
    unsigned* __restrict__ flags,        // 64 x stride16
    unsigned* __restrict__ xwcnt,        // 64 x stride16
    const float* __restrict__ ctx,
    __hip_bfloat16* __restrict__ ctxT,
    const float* __restrict__ W_out,
    __hip_bfloat16* __restrict__ Wout_h,
    __hip_bfloat16* __restrict__ Wout_l)
{
    __shared__ __align__(16) char smem_raw[82432];
    int bid = blockIdx.x;
    int tid = threadIdx.x;
    int lane = tid & 63, w = tid >> 6;
    int fr = lane & 15, fq = lane >> 4;

    if (bid < RBLK) {
        // ================= RECURRENCE (r10 structure, XW2 gated by xwcnt) =============
        __hip_bfloat16* Wh = (__hip_bfloat16*)smem_raw;            // 32KB swizzled
        __hip_bfloat16* Wl = (__hip_bfloat16*)(smem_raw + 32768);  // 32KB
        float (*gl)[32][33] = (float(*)[32][33])(smem_raw + 65536);// 16.9KB
        int bi = bid;

        // stage Whh slice into LDS (rows jl: gate g=jl>>3, cell bi*8+(jl&7))
        {
            int jl = tid >> 3, ck8 = tid & 7;
            int grow = (jl >> 3) * NH + bi * CPB + (jl & 7);
            const short8* srcH = (const short8*)(Whh_h + (size_t)grow * NH);
            const short8* srcL = (const short8*)(Whh_l + (size_t)grow * NH);
            #pragma unroll
            for (int cc = 0; cc < 8; cc++) {
                int ck = ck8 * 8 + cc;
                int sw = (ck * 16) ^ ((jl & 7) << 4);
                *(short8*)((char*)Wh + jl * 1024 + sw) = srcH[ck];
                *(short8*)((char*)Wl + jl * 1024 + sw) = srcL[ck];
            }
        }
        int eb  = tid >> 2;
        int ec0 = (tid & 3) * 2;
        int ebl = eb & 31, mhalf = eb >> 5;
        float creg[2];
        creg[0] = c0[eb * NH + bi*CPB + ec0];
        creg[1] = c0[eb * NH + bi*CPB + ec0 + 1];
        // wait for XW[t=0], then gather
        {
            int guard = 0;
            while (__hip_atomic_load(&xwcnt[0], __ATOMIC_RELAXED, __HIP_MEMORY_SCOPE_AGENT) < 8u) {
                __builtin_amdgcn_s_sleep(1);
                if (++guard > (1<<22)) break;
            }
        }
        float xw[8];
        #pragma unroll
        for (int g = 0; g < 4; g++)
          #pragma unroll
          for (int u = 0; u < 2; u++)
            xw[g*2+u] = XW2[(size_t)eb*G4 + g*NH + bi*CPB + ec0 + u];   // t=0
        __syncthreads();

        int m0 = (w & 1) * 32;
        int kbase = (w >> 1) * 256;

        for (int t = 0; t < NT_; t++) {
            const __hip_bfloat16* Ah = hs_h + (size_t)t * NB * NH;
            const __hip_bfloat16* Al = hs_l + (size_t)t * NB * NH;

            // burst-preload A fragments (dependence-free)
            short8 Aregh[2][8], Aregl[2][8];
            #pragma unroll
            for (int i = 0; i < 2; i++) {
                const __hip_bfloat16* rowH = Ah + (size_t)(m0 + i*16 + fr) * NH + kbase + fq*8;
                const __hip_bfloat16* rowL = Al + (size_t)(m0 + i*16 + fr) * NH + kbase + fq*8;
                #pragma unroll
                for (int k8 = 0; k8 < 8; k8++) {
                    Aregh[i][k8] = ld8b(rowH + k8*32);
                    Aregl[i][k8] = ld8b(rowL + k8*32);
                }
            }

            f32x4 acc[2][2] = {};
            #pragma unroll
            for (int k8 = 0; k8 < 8; k8++) {
                short8 b_h[2], b_l[2];
                #pragma unroll
                for (int j = 0; j < 2; j++) {
                    int jl = j*16 + fr;
                    int byt = jl*1024 + ((((kbase + k8*32 + fq*8)*2)) ^ ((jl & 7) << 4));
                    b_h[j] = *(const short8*)((const char*)Wh + byt);
                    b_l[j] = *(const short8*)((const char*)Wl + byt);
                }
                #pragma unroll
                for (int i = 0; i < 2; i++)
                    #pragma unroll
                    for (int j = 0; j < 2; j++) {
                        acc[i][j] = __builtin_amdgcn_mfma_f32_16x16x32_bf16(Aregh[i][k8], b_h[j], acc[i][j], 0,0,0);
                        acc[i][j] = __builtin_amdgcn_mfma_f32_16x16x32_bf16(Aregh[i][k8], b_l[j], acc[i][j], 0,0,0);
                        acc[i][j] = __builtin_amdgcn_mfma_f32_16x16x32_bf16(Aregl[i][k8], b_h[j], acc[i][j], 0,0,0);
                    }
            }
            #pragma unroll
            for (int i = 0; i < 2; i++)
              #pragma unroll
              for (int j = 0; j < 2; j++)
                #pragma unroll
                for (int r = 0; r < 4; r++)
                    gl[w][i*16 + fq*4 + r][j*16 + fr] = acc[i][j][r];
            __syncthreads();

            // cell elementwise
            float hv[2];
            #pragma unroll
            for (int u = 0; u < 2; u++) {
                int cl = ec0 + u;
                float gi = gl[mhalf][ebl][cl]      + gl[2+mhalf][ebl][cl]      + xw[u];
                float gf = gl[mhalf][ebl][8 + cl]  + gl[2+mhalf][ebl][8 + cl]  + xw[2+u];
                float gg = gl[mhalf][ebl][16 + cl] + gl[2+mhalf][ebl][16 + cl] + xw[4+u];
                float go = gl[mhalf][ebl][24 + cl] + gl[2+mhalf][ebl][24 + cl] + xw[6+u];
                float ct = fsigm(gf)*creg[u] + fsigm(gi)*ftanh(gg);
                hv[u] = fsigm(go)*ftanh(ct);
                creg[u] = ct;
            }
            int hcol = bi*CPB + ec0;
            size_t hoff = (size_t)(t+1)*NB*NH + (size_t)eb*NH + hcol;
            unsigned short h0b = (unsigned short)f2bs(hv[0]);
            unsigned short h1b = (unsigned short)f2bs(hv[1]);
            unsigned ph = (unsigned)h0b | ((unsigned)h1b << 16);
            unsigned short l0b = (unsigned short)f2bs(hv[0] - bs2f((short)h0b));
            unsigned short l1b = (unsigned short)f2bs(hv[1] - bs2f((short)h1b));
            unsigned pl = (unsigned)l0b | ((unsigned)l1b << 16);
            __hip_atomic_store((unsigned*)&hs_h[hoff], ph, __ATOMIC_RELAXED, __HIP_MEMORY_SCOPE_AGENT);
            __hip_atomic_store((unsigned*)&hs_l[hoff], pl, __ATOMIC_RELAXED, __HIP_MEMORY_SCOPE_AGENT);
            if (t == NT_-1) {
                *(float2*)&hT[(size_t)eb*NH + hcol] = make_float2(hv[0], hv[1]);
                *(float2*)&cT[(size_t)eb*NH + hcol] = make_float2(creg[0], creg[1]);
            }

            // distributed-flag grid barrier
            asm volatile("s_waitcnt vmcnt(0)" ::: "memory");
            __syncthreads();
            if (tid == 0)
                __hip_atomic_store(&flags[bi*16], (unsigned)(t+1), __ATOMIC_RELAXED, __HIP_MEMORY_SCOPE_AGENT);
            // XW gather for t+1 (gated by xwcnt; done during the flag-wait window)
            if (t + 1 < NT_) {
                int guard = 0;
                while (__hip_atomic_load(&xwcnt[(t+1)*16], __ATOMIC_RELAXED, __HIP_MEMORY_SCOPE_AGENT) < 8u) {
                    __builtin_amdgcn_s_sleep(1);
                    if (++guard > (1<<22)) break;
                }
                #pragma unroll
                for (int g = 0; g < 4; g++)
                  #pragma unroll
                  for (int u = 0; u < 2; u++)
                    xw[g*2+u] = XW2[((size_t)(t+1)*NB + eb)*G4 + g*NH + bi*CPB + ec0 + u];
            }
            // every wave polls all 64 flags (64 lanes in parallel)
            {
                unsigned target = (unsigned)(t+1);
                int guard = 0;
                while (__hip_atomic_load(&flags[lane*16], __ATOMIC_RELAXED, __HIP_MEMORY_SCOPE_AGENT) < target) {
                    __builtin_amdgcn_s_sleep(1);
                    if (++guard > (1<<22)) break;
                }
            }
        }
    } else if (bid < RBLK + XWB) {
        // ================= gemm_xw role: one t, 4 waves x 64x64 n-tiles ===============
        // XW2[t][b][n] = X[b,t,:] . Wih[n,:] + b_ih[n] + b_hh[n]
        int e  = bid - RBLK;
        int t0 = e >> 3;                 // t ascending with blockIdx -> early steps first
        int n0 = ((e & 7) * 4 + w) * 64;
        f32x4 acc[4][4] = {};
        for (int kk = 0; kk < NI; kk += 32) {
            short8 ah[4], al[4], bh[4], bl[4];
            #pragma unroll
            for (int i = 0; i < 4; i++) {
                size_t off = ((size_t)(i*16+fr)*NT_ + t0)*NI + kk + fq*8;
                ah[i] = ld8b(Xh + off);
                al[i] = ld8b(Xl + off);
            }
            #pragma unroll
            for (int j = 0; j < 4; j++) {
                bh[j] = ld8b(Wih_h + (size_t)(n0+j*16+fr)*NI + kk + fq*8);
                bl[j] = ld8b(Wih_l + (size_t)(n0+j*16+fr)*NI + kk + fq*8);
            }
            #pragma unroll
            for (int i = 0; i < 4; i++)
                #pragma unroll
                for (int j = 0; j < 4; j++) {
                    acc[i][j] = __builtin_amdgcn_mfma_f32_16x16x32_bf16(ah[i], bh[j], acc[i][j], 0,0,0);
                    acc[i][j] = __builtin_amdgcn_mfma_f32_16x16x32_bf16(ah[i], bl[j], acc[i][j], 0,0,0);
                    acc[i][j] = __builtin_amdgcn_mfma_f32_16x16x32_bf16(al[i], bh[j], acc[i][j], 0,0,0);
                }
        }
        // write-through atomic stores (visible at L3 without kernel boundary)
        #pragma unroll
        for (int i = 0; i < 4; i++)
          #pragma unroll
          for (int j = 0; j < 4; j++)
            #pragma unroll
            for (int r = 0; r < 4; r++) {
                int b = i*16 + fq*4 + r;
                int n = n0 + j*16 + fr;
                float v = acc[i][j][r] + b_ih[n] + b_hh[n];
                union { float f; unsigned u; } cv; cv.f = v;
                __hip_atomic_store((unsigned*)&XW2[((size_t)t0*NB + b)*G4 + n], cv.u,
                                   __ATOMIC_RELAXED, __HIP_MEMORY_SCOPE_AGENT);
            }
        asm volatile("s_waitcnt vmcnt(0)" ::: "memory");   // data at coherence point
        __syncthreads();                                   // all 4 waves done
        if (tid == 0)
            __hip_atomic_fetch_add(&xwcnt[t0*16], 1u, __ATOMIC_RELAXED, __HIP_MEMORY_SCOPE_AGENT);
    } else if (bid < RBLK + XWB + TRB) {
        // ================= transpose_ctx role ========================================
        float (*tile)[65] = (float(*)[65])smem_raw;
        int tr = bid - (RBLK + XWB);
        int s0 = (tr & 7) * 64, h0 = ((tr >> 3) & 7) * 64, b = tr >> 6;
        int tx = tid & 63, ty = tid >> 6;
        for (int i = 0; i < 16; i++) {
            int s = i*4 + ty;
            tile[s][tx] = ctx[(size_t)(s0+s)*NB*NH + (size_t)b*NH + h0 + tx];
        }
        __syncthreads();
        for (int i = 0; i < 16; i++) {
            int h = i*4 + ty;
            ctxT[(size_t)b*NH*NS + (size_t)(h0+h)*NS + s0 + tx] = __float2bfloat16(tile[tx][h]);
        }
    } else {
        // ================= W_out conv_split role =====================================
        int wv = bid - (RBLK + XWB + TRB);
        for (int i = wv*256 + tid; i < NH*H2; i += WOB*256) {
            float x = W_out[i];
            __hip_bfloat16 h = __float2bfloat16(x);
            Wout_h[i] = h;
            Wout_l[i] = __float2bfloat16(x - __bfloat162float(h));
        }
    }
}

// ---------------- scores[b,t,s] = h[b,t,:] . ctx[s,b,:]  (A from hs hi/lo) ----------------
__global__ __launch_bounds__(256) void gemm_scores(const __hip_bfloat16* __restrict__ hs_h,
                                                   const __hip_bfloat16* __restrict__ hs_l,
                                                   const float* __restrict__ ctx,
                                                   float* __restrict__ scores) {
    int wid = blockIdx.x*4 + (threadIdx.x>>6);
    int lane = threadIdx.x & 63;
    int b  = wid >> 3;
    int n0 = (wid & 7) * 64;
    int fr = lane & 15, fq = lane >> 4;
    const __hip_bfloat16* Abh = hs_h + NB*NH + (size_t)b*NH;   // slot t+1, row stride NB*NH
    const __hip_bfloat16* Abl = hs_l + NB*NH + (size_t)b*NH;
    const float* Bb = ctx + (size_t)b*NH;
    f32x4 acc[4][4] = {};
    for (int kk = 0; kk < NH; kk += 32) {
        short8 ah[4], al[4], bh[4], bl[4];
        #pragma unroll
        for (int i = 0; i < 4; i++) {
            size_t off = (size_t)(i*16+fr)*NB*NH + kk + fq*8;
            ah[i] = ld8b(Abh + off);
            al[i] = ld8b(Abl + off);
        }
        #pragma unroll
        for (int j = 0; j < 4; j++) ld8f2(Bb + (size_t)(n0+j*16+fr)*NB*NH + kk + fq*8, bh[j], bl[j]);
        #pragma unroll
        for (int i = 0; i < 4; i++)
            #pragma unroll
            for (int j = 0; j < 4; j++) {
                acc[i][j] = __builtin_amdgcn_mfma_f32_16x16x32_bf16(ah[i], bh[j], acc[i][j], 0,0,0);
                acc[i][j] = __builtin_amdgcn_mfma_f32_16x16x32_bf16(ah[i], bl[j], acc[i][j], 0,0,0);
                acc[i][j] = __builtin_amdgcn_mfma_f32_16x16x32_bf16(al[i], bh[j], acc[i][j], 0,0,0);
            }
    }
    #pragma unroll
    for (int i = 0; i < 4; i++)
      #pragma unroll
      for (int j = 0; j < 4; j++)
        #pragma unroll
        for (int r = 0; r < 4; r++) {
            int t = i*16 + fq*4 + r;
            int s = n0 + j*16 + fr;
            scores[((size_t)b*NT_ + t)*NS + s] = acc[i][j][r];
        }
}

// ---------------- row softmax over S, output attn hi/lo bf16 ----------------
__global__ __launch_bounds__(256) void softmax_rows(const float* __restrict__ scores,
                                                    __hip_bfloat16* __restrict__ ah,
                                                    __hip_bfloat16* __restrict__ al) {
    int row = blockIdx.x*4 + (threadIdx.x>>6);
    int lane = threadIdx.x & 63;
    const float* r = scores + (size_t)row*NS;
    float v[8], mx = -1e30f;
    #pragma unroll
    for (int i = 0; i < 8; i++) { v[i] = r[lane + i*64]; mx = fmaxf(mx, v[i]); }
    #pragma unroll
    for (int off = 32; off; off >>= 1) mx = fmaxf(mx, __shfl_xor(mx, off));
    float sum = 0.f;
    #pragma unroll
    for (int i = 0; i < 8; i++) { v[i] = __expf(v[i]-mx); sum += v[i]; }
    #pragma unroll
    for (int off = 32; off; off >>= 1) sum += __shfl_xor(sum, off);
    float inv = 1.f/sum;
    #pragma unroll
    for (int i = 0; i < 8; i++) {
        float a = v[i]*inv;
        __hip_bfloat16 h = __float2bfloat16(a);
        ah[(size_t)row*NS + lane + i*64] = h;
        al[(size_t)row*NS + lane + i*64] = __float2bfloat16(a - __bfloat162float(h));
    }
}

// ---------------- Wc[b,t,h] = sum_s attn[b,t,s]*ctxT[b,h,s]  (fp32 out) ----------------
__global__ __launch_bounds__(256) void gemm_wc(const __hip_bfloat16* __restrict__ Ah,
                                               const __hip_bfloat16* __restrict__ Al,
                                               const __hip_bfloat16* __restrict__ ctxT,
                                               float* __restrict__ Wc) {
    int wid = blockIdx.x*4 + (threadIdx.x>>6);
    int lane = threadIdx.x & 63;
    int b  = wid >> 3;
    int n0 = (wid & 7) * 64;
    int fr = lane & 15, fq = lane >> 4;
    const __hip_bfloat16* Abh = Ah + (size_t)b*NT_*NS;
    const __hip_bfloat16* Abl = Al + (size_t)b*NT_*NS;
    const __hip_bfloat16* Bb  = ctxT + (size_t)b*NH*NS;
    f32x4 acc[4][4] = {};
    for (int kk = 0; kk < NS; kk += 32) {
        short8 ah[4], al[4], bb[4];
        #pragma unroll
        for (int i = 0; i < 4; i++) {
            ah[i] = ld8b(Abh + (size_t)(i*16+fr)*NS + kk + fq*8);
            al[i] = ld8b(Abl + (size_t)(i*16+fr)*NS + kk + fq*8);
        }
        #pragma unroll
        for (int j = 0; j < 4; j++) bb[j] = ld8b(Bb + (size_t)(n0+j*16+fr)*NS + kk + fq*8);
        #pragma unroll
        for (int i = 0; i < 4; i++)
            #pragma unroll
            for (int j = 0; j < 4; j++) {
                acc[i][j] = __builtin_amdgcn_mfma_f32_16x16x32_bf16(ah[i], bb[j], acc[i][j], 0,0,0);
                acc[i][j] = __builtin_amdgcn_mfma_f32_16x16x32_bf16(al[i], bb[j], acc[i][j], 0,0,0);
            }
    }
    #pragma unroll
    for (int i = 0; i < 4; i++)
      #pragma unroll
      for (int j = 0; j < 4; j++)
        #pragma unroll
        for (int r = 0; r < 4; r++) {
            int t = i*16 + fq*4 + r;
            int h = n0 + j*16 + fr;
            Wc[((size_t)b*NT_ + t)*NH + h] = acc[i][j][r];
        }
}

// ---------------- out = tanh([Wc|h] @ W_out^T)  (M=4096,N=512,K=1024) ----------------
__global__ __launch_bounds__(256) void gemm_out(const float* __restrict__ Wc,
                                                const __hip_bfloat16* __restrict__ hs_h,
                                                const __hip_bfloat16* __restrict__ hs_l,
                                                const __hip_bfloat16* __restrict__ Wh,
                                                const __hip_bfloat16* __restrict__ Wl,
                                                float* __restrict__ out) {
    int wid = blockIdx.x*4 + (threadIdx.x>>6);
    int lane = threadIdx.x & 63;
    int m0 = (wid >> 3) * 64;
    int n0 = (wid & 7) * 64;
    int fr = lane & 15, fq = lane >> 4;
    f32x4 acc[4][4] = {};
    // half 0: Wc (fp32, split on the fly), K cols [0,512)
    for (int kk = 0; kk < NH; kk += 32) {
        short8 ah[4], al[4], bh[4], bl[4];
        #pragma unroll
        for (int i = 0; i < 4; i++) ld8f2(Wc + (size_t)(m0+i*16+fr)*NH + kk + fq*8, ah[i], al[i]);
        #pragma unroll
        for (int j = 0; j < 4; j++) {
            bh[j] = ld8b(Wh + (size_t)(n0+j*16+fr)*H2 + kk + fq*8);
            bl[j] = ld8b(Wl + (size_t)(n0+j*16+fr)*H2 + kk + fq*8);
        }
        #pragma unroll
        for (int i = 0; i < 4; i++)
            #pragma unroll
            for (int j = 0; j < 4; j++) {
                acc[i][j] = __builtin_amdgcn_mfma_f32_16x16x32_bf16(ah[i], bh[j], acc[i][j], 0,0,0);
                acc[i][j] = __builtin_amdgcn_mfma_f32_16x16x32_bf16(ah[i], bl[j], acc[i][j], 0,0,0);
                acc[i][j] = __builtin_amdgcn_mfma_f32_16x16x32_bf16(al[i], bh[j], acc[i][j], 0,0,0);
            }
    }
    // half 1: h from hs time-series (bf16 hi/lo), K cols [512,1024)
    {
        const __hip_bfloat16* A2h = hs_h + NB*NH + (size_t)(m0>>6)*NH;  // row rloc=t -> slot t+1
        const __hip_bfloat16* A2l = hs_l + NB*NH + (size_t)(m0>>6)*NH;
        for (int kk = 0; kk < NH; kk += 32) {
            short8 ah[4], al[4], bh[4], bl[4];
            #pragma unroll
            for (int i = 0; i < 4; i++) {
                size_t off = (size_t)(i*16+fr)*NB*NH + kk + fq*8;
                ah[i] = ld8b(A2h + off);
                al[i] = ld8b(A2l + off);
            }
            #pragma unroll
            for (int j = 0; j < 4; j++) {
                bh[j] = ld8b(Wh + (size_t)(n0+j*16+fr)*H2 + NH + kk + fq*8);
                bl[j] = ld8b(Wl + (size_t)(n0+j*16+fr)*H2 + NH + kk + fq*8);
            }
            #pragma unroll
            for (int i = 0; i < 4; i++)
                #pragma unroll
                for (int j = 0; j < 4; j++) {
                    acc[i][j] = __builtin_amdgcn_mfma_f32_16x16x32_bf16(ah[i], bh[j], acc[i][j], 0,0,0);
                    acc[i][j] = __builtin_amdgcn_mfma_f32_16x16x32_bf16(ah[i], bl[j], acc[i][j], 0,0,0);
                    acc[i][j] = __builtin_amdgcn_mfma_f32_16x16x32_bf16(al[i], bh[j], acc[i][j], 0,0,0);
                }
        }
    }
    #pragma unroll
    for (int i = 0; i < 4; i++)
      #pragma unroll
      for (int j = 0; j < 4; j++)
        #pragma unroll
        for (int r = 0; r < 4; r++) {
            int m = m0 + i*16 + fq*4 + r;
            int n = n0 + j*16 + fr;
            out[(size_t)m*NH + n] = ftanh(acc[i][j][r]);
        }
}

// ---------------- workspace layout (authoritative offsets in kernel_launch) ----------------
// XW2 fp32 (T,B,4H) @0 (33.5MB); scores/attn overlay @0 after recurrence.
// hs @33.5MB; sync (flags+xwcnt, 8KB) @42.07MB; Wc / Xh/Xl overlay @42.08MB;
// weights @50.47MB; ctxT @60.96MB. (r9 lesson: no 64MB ctx presplit — doesn't fit.)

extern "C" void kernel_launch(void* const* d_in, const int* in_sizes, int n_in,
                              void* d_out, int out_size, void* d_ws, size_t ws_size,
                              hipStream_t stream) {
    const float* input = (const float*)d_in[0];
    const float* h0    = (const float*)d_in[1];
    const float* c0    = (const float*)d_in[2];
    const float* ctx   = (const float*)d_in[3];
    const float* W_ih  = (const float*)d_in[4];
    const float* b_ih  = (const float*)d_in[5];
    const float* W_hh  = (const float*)d_in[6];
    const float* b_hh  = (const float*)d_in[7];
    const float* W_out = (const float*)d_in[8];
    float* out = (float*)d_out;

    const size_t OFF_XW     = 0;          // 33,554,432
    const size_t OFF_SCORES = 0;          //  8,388,608 (after recurrence)
    const size_t OFF_ATTN_H = 8388608;    //  4,194,304
    const size_t OFF_ATTN_L = 12582912;   //  4,194,304
    const size_t OFF_HS_H   = 33554432;   //  4,259,840
    const size_t OFF_HS_L   = 37814272;   //  4,259,840
    const size_t OFF_SYNC   = 42074112;   //      8,192 (flags 4KB + xwcnt 4KB)
    const size_t OFF_WC     = 42082304;   //  8,388,608  [Xh/Xl overlay pre-recurrence]
    const size_t OFF_XH     = 42082304;   //  4,194,304
    const size_t OFF_XL     = 46276608;   //  4,194,304
    const size_t OFF_WIH_H  = 50470912;   //  2,097,152
    const size_t OFF_WIH_L  = 52568064;   //  2,097,152
    const size_t OFF_WHH_H  = 54665216;   //  2,097,152
    const size_t OFF_WHH_L  = 56762368;   //  2,097,152
    const size_t OFF_WOUT_H = 58859520;   //  1,048,576
    const size_t OFF_WOUT_L = 59908096;   //  1,048,576
    const size_t OFF_CTXT   = 60956672;   // 33,554,432 -> end 94,511,104
    if (ws_size < 94511104u) return;  // fail loudly (d_out stays poisoned)

    char* ws = (char*)d_ws;
    float*          XW2    = (float*)(ws + OFF_XW);
    float*          scores = (float*)(ws + OFF_SCORES);
    __hip_bfloat16* attn_h = (__hip_bfloat16*)(ws + OFF_ATTN_H);
    __hip_bfloat16* attn_l = (__hip_bfloat16*)(ws + OFF_ATTN_L);
    __hip_bfloat16* hs_h   = (__hip_bfloat16*)(ws + OFF_HS_H);
    __hip_bfloat16* hs_l   = (__hip_bfloat16*)(ws + OFF_HS_L);
    unsigned*       sync   = (unsigned*)(ws + OFF_SYNC);
    unsigned*       flags  = sync;          // 64 x stride16 u32
    unsigned*       xwcnt  = sync + 1024;   // 64 x stride16 u32
    float*          Wc     = (float*)(ws + OFF_WC);
    __hip_bfloat16* Xh     = (__hip_bfloat16*)(ws + OFF_XH);
    __hip_bfloat16* Xl     = (__hip_bfloat16*)(ws + OFF_XL);
    __hip_bfloat16* Wih_h  = (__hip_bfloat16*)(ws + OFF_WIH_H);
    __hip_bfloat16* Wih_l  = (__hip_bfloat16*)(ws + OFF_WIH_L);
    __hip_bfloat16* Whh_h  = (__hip_bfloat16*)(ws + OFF_WHH_H);
    __hip_bfloat16* Whh_l  = (__hip_bfloat16*)(ws + OFF_WHH_L);
    __hip_bfloat16* Wout_h = (__hip_bfloat16*)(ws + OFF_WOUT_H);
    __hip_bfloat16* Wout_l = (__hip_bfloat16*)(ws + OFF_WOUT_L);
    __hip_bfloat16* ctxT   = (__hip_bfloat16*)(ws + OFF_CTXT);

    conv_split<<<2048, 256, 0, stream>>>(W_ih, Wih_h, Wih_l, G4*NI);
    conv_split<<<2048, 256, 0, stream>>>(W_hh, Whh_h, Whh_l, G4*NH);
    conv_split<<<2048, 256, 0, stream>>>(input, Xh, Xl, BT*NI);
    hseq0_init<<<128, 256, 0, stream>>>(h0, hs_h, hs_l, sync);

    float* hT = out + (size_t)BT*NH;
    float* cT = hT + NB*NH;
    lstm_mega<<<GRID_MEGA, 256, 0, stream>>>(c0, Whh_h, Whh_l, Xh, Xl, Wih_h, Wih_l,
                                             b_ih, b_hh, XW2, hs_h, hs_l, hT, cT,
                                             flags, xwcnt, ctx, ctxT, W_out, Wout_h, Wout_l);

    gemm_scores<<<128, 256, 0, stream>>>(hs_h, hs_l, ctx, scores);
    softmax_rows<<<1024, 256, 0, stream>>>(scores, attn_h, attn_l);
    gemm_wc<<<128, 256, 0, stream>>>(attn_h, attn_l, ctxT, Wc);
    gemm_out<<<128, 256, 0, stream>>>(Wc, hs_h, hs_l, Wout_h, Wout_l, out);
}

// Round 13
// 627.593 us; speedup vs baseline: 1.7111x; 1.0127x over previous
//
#include <hip/hip_runtime.h>
#include <hip/hip_bf16.h>

// Problem constants
#define NB 64      // batch
#define NT_ 64     // time steps
#define NS 512     // source positions
#define NI 512     // input dim
#define NH 512     // hidden
#define G4 2048    // 4*H
#define H2 1024    // 2*H
#define BT (NB*NT_)
#define RBLK 64    // recurrence blocks
#define CPB 8      // cells per block
// mega-kernel role ranges
#define XWB 512    // gemm_xw blocks (64 t x 8 n-groups)
#define TRB 4096   // transpose blocks (8 s x 8 h x 64 b)
#define WOB 128    // W_out conv blocks
#define GRID_MEGA (RBLK + XWB + TRB + WOB)

typedef __attribute__((ext_vector_type(8))) short short8;   // 8 bf16 (4 VGPRs)
typedef __attribute__((ext_vector_type(4))) float f32x4;    // MFMA accumulator

__device__ __forceinline__ short f2bs(float f) {
    __hip_bfloat16 h = __float2bfloat16(f);
    return *reinterpret_cast<short*>(&h);
}
__device__ __forceinline__ float bs2f(short s) {
    unsigned int u = ((unsigned int)(unsigned short)s) << 16;
    union { unsigned int u; float f; } c; c.u = u; return c.f;
}
__device__ __forceinline__ short8 ld8b(const __hip_bfloat16* p) {
    return *reinterpret_cast<const short8*>(p);
}
// load 8 fp32, produce hi & lo bf16 fragments (x ~= hi + lo, rel err ~2^-16)
__device__ __forceinline__ void ld8f2(const float* p, short8& hi, short8& lo) {
    float4 a = *reinterpret_cast<const float4*>(p);
    float4 b = *reinterpret_cast<const float4*>(p + 4);
    float v[8] = {a.x,a.y,a.z,a.w,b.x,b.y,b.z,b.w};
    #pragma unroll
    for (int i = 0; i < 8; i++) {
        short h = f2bs(v[i]);
        hi[i] = h;
        lo[i] = f2bs(v[i] - bs2f(h));
    }
}
__device__ __forceinline__ float fsigm(float x){ return 1.f/(1.f + __expf(-x)); }
__device__ __forceinline__ float ftanh(float x){ float e = __expf(2.f*x); return 1.f - 2.f/(e + 1.f); }

// h0 -> hs slot 0 (hi/lo); zero flags (64 x stride16 u32) + xwcnt (64 x stride16 u32)
__global__ __launch_bounds__(256) void hseq0_init(const float* __restrict__ h0,
                                                  __hip_bfloat16* __restrict__ hs_h,
                                                  __hip_bfloat16* __restrict__ hs_l,
                                                  unsigned* __restrict__ sync) {
    int i = blockIdx.x*256 + threadIdx.x;
    if (i < 2048) sync[i] = 0u;      // flags[0..1023] + xwcnt[1024..2047]
    if (i < NB*NH) {
        float x = h0[i];
        __hip_bfloat16 h = __float2bfloat16(x);
        hs_h[i] = h;
        hs_l[i] = __float2bfloat16(x - __bfloat162float(h));
    }
}

// =====================================================================================
// MEGA KERNEL: blocks 0-63 recurrence | 64-575 gemm_xw | 576-4671 transpose | rest Wout
// All fp32->bf16 hi/lo conversion folded into consumers (bit-identical to conv_split).
// LDS union (83KB) -> 1 block/CU for all roles.
// =====================================================================================
__global__ __launch_bounds__(256, 1) void lstm_mega(
    const float* __restrict__ c0,
    const float* __restrict__ W_hh,      // raw fp32 — split during LDS staging
    const float* __restrict__ input,     // raw fp32 — split in xw role
    const float* __restrict__ W_ih,      // raw fp32 — split in xw role
    const float* __restrict__ b_ih,
    const float* __restrict__ b_hh,
    float* __restrict__ XW2,             // (T,B,4H) fp32, t-major
    __hip_bfloat16* __restrict__ hs_h,   // (65,B,H) bf16 time-series
    __hip_bfloat16* __restrict__ hs_l,
    float* __restrict__ hT, float* __restrict__ cT,
    unsigned* __restrict__ flags,        // 64 x stride16
    unsigned* __restrict__ xwcnt,        // 64 x stride16
    const float* __restrict__ ctx,
    __hip_bfloat16* __restrict__ ctxT,
    const float* __restrict__ W_out,
    __hip_bfloat16* __restrict__ Wout_h,
    __hip_bfloat16* __restrict__ Wout_l)
{
    __shared__ __align__(16) char smem_raw[82432];
    int bid = blockIdx.x;
    int tid = threadIdx.x;
    int lane = tid & 63, w = tid >> 6;
    int fr = lane & 15, fq = lane >> 4;

    if (bid < RBLK) {
        // ================= RECURRENCE (r10 structure, XW2 gated by xwcnt) =============
        __hip_bfloat16* Wh = (__hip_bfloat16*)smem_raw;            // 32KB swizzled
        __hip_bfloat16* Wl = (__hip_bfloat16*)(smem_raw + 32768);  // 32KB
        float (*gl)[32][33] = (float(*)[32][33])(smem_raw + 65536);// 16.9KB
        int bi = bid;

        // stage Whh slice into LDS from RAW FP32, splitting hi/lo in-register
        // (rows jl: gate g=jl>>3, cell bi*8+(jl&7)); same swizzled layout as r12
        {
            int jl = tid >> 3, ck8 = tid & 7;
            int grow = (jl >> 3) * NH + bi * CPB + (jl & 7);
            const float* src = W_hh + (size_t)grow * NH;
            #pragma unroll
            for (int cc = 0; cc < 8; cc++) {
                int ck = ck8 * 8 + cc;                       // 8-float chunk 0..63
                short8 hi, lo;
                ld8f2(src + ck*8, hi, lo);
                int sw = (ck * 16) ^ ((jl & 7) << 4);
                *(short8*)((char*)Wh + jl * 1024 + sw) = hi;
                *(short8*)((char*)Wl + jl * 1024 + sw) = lo;
            }
        }
        int eb  = tid >> 2;
        int ec0 = (tid & 3) * 2;
        int ebl = eb & 31, mhalf = eb >> 5;
        float creg[2];
        creg[0] = c0[eb * NH + bi*CPB + ec0];
        creg[1] = c0[eb * NH + bi*CPB + ec0 + 1];
        // wait for XW[t=0], then gather
        {
            int guard = 0;
            while (__hip_atomic_load(&xwcnt[0], __ATOMIC_RELAXED, __HIP_MEMORY_SCOPE_AGENT) < 8u) {
                __builtin_amdgcn_s_sleep(1);
                if (++guard > (1<<22)) break;
            }
        }
        float xw[8];
        #pragma unroll
        for (int g = 0; g < 4; g++)
          #pragma unroll
          for (int u = 0; u < 2; u++)
            xw[g*2+u] = XW2[(size_t)eb*G4 + g*NH + bi*CPB + ec0 + u];   // t=0
        __syncthreads();

        int m0 = (w & 1) * 32;
        int kbase = (w >> 1) * 256;

        for (int t = 0; t < NT_; t++) {
            const __hip_bfloat16* Ah = hs_h + (size_t)t * NB * NH;
            const __hip_bfloat16* Al = hs_l + (size_t)t * NB * NH;

            // burst-preload A fragments (dependence-free)
            short8 Aregh[2][8], Aregl[2][8];
            #pragma unroll
            for (int i = 0; i < 2; i++) {
                const __hip_bfloat16* rowH = Ah + (size_t)(m0 + i*16 + fr) * NH + kbase + fq*8;
                const __hip_bfloat16* rowL = Al + (size_t)(m0 + i*16 + fr) * NH + kbase + fq*8;
                #pragma unroll
                for (int k8 = 0; k8 < 8; k8++) {
                    Aregh[i][k8] = ld8b(rowH + k8*32);
                    Aregl[i][k8] = ld8b(rowL + k8*32);
                }
            }

            f32x4 acc[2][2] = {};
            #pragma unroll
            for (int k8 = 0; k8 < 8; k8++) {
                short8 b_h[2], b_l[2];
                #pragma unroll
                for (int j = 0; j < 2; j++) {
                    int jl = j*16 + fr;
                    int byt = jl*1024 + ((((kbase + k8*32 + fq*8)*2)) ^ ((jl & 7) << 4));
                    b_h[j] = *(const short8*)((const char*)Wh + byt);
                    b_l[j] = *(const short8*)((const char*)Wl + byt);
                }
                #pragma unroll
                for (int i = 0; i < 2; i++)
                    #pragma unroll
                    for (int j = 0; j < 2; j++) {
                        acc[i][j] = __builtin_amdgcn_mfma_f32_16x16x32_bf16(Aregh[i][k8], b_h[j], acc[i][j], 0,0,0);
                        acc[i][j] = __builtin_amdgcn_mfma_f32_16x16x32_bf16(Aregh[i][k8], b_l[j], acc[i][j], 0,0,0);
                        acc[i][j] = __builtin_amdgcn_mfma_f32_16x16x32_bf16(Aregl[i][k8], b_h[j], acc[i][j], 0,0,0);
                    }
            }
            #pragma unroll
            for (int i = 0; i < 2; i++)
              #pragma unroll
              for (int j = 0; j < 2; j++)
                #pragma unroll
                for (int r = 0; r < 4; r++)
                    gl[w][i*16 + fq*4 + r][j*16 + fr] = acc[i][j][r];
            __syncthreads();

            // cell elementwise
            float hv[2];
            #pragma unroll
            for (int u = 0; u < 2; u++) {
                int cl = ec0 + u;
                float gi = gl[mhalf][ebl][cl]      + gl[2+mhalf][ebl][cl]      + xw[u];
                float gf = gl[mhalf][ebl][8 + cl]  + gl[2+mhalf][ebl][8 + cl]  + xw[2+u];
                float gg = gl[mhalf][ebl][16 + cl] + gl[2+mhalf][ebl][16 + cl] + xw[4+u];
                float go = gl[mhalf][ebl][24 + cl] + gl[2+mhalf][ebl][24 + cl] + xw[6+u];
                float ct = fsigm(gf)*creg[u] + fsigm(gi)*ftanh(gg);
                hv[u] = fsigm(go)*ftanh(ct);
                creg[u] = ct;
            }
            int hcol = bi*CPB + ec0;
            size_t hoff = (size_t)(t+1)*NB*NH + (size_t)eb*NH + hcol;
            unsigned short h0b = (unsigned short)f2bs(hv[0]);
            unsigned short h1b = (unsigned short)f2bs(hv[1]);
            unsigned ph = (unsigned)h0b | ((unsigned)h1b << 16);
            unsigned short l0b = (unsigned short)f2bs(hv[0] - bs2f((short)h0b));
            unsigned short l1b = (unsigned short)f2bs(hv[1] - bs2f((short)h1b));
            unsigned pl = (unsigned)l0b | ((unsigned)l1b << 16);
            __hip_atomic_store((unsigned*)&hs_h[hoff], ph, __ATOMIC_RELAXED, __HIP_MEMORY_SCOPE_AGENT);
            __hip_atomic_store((unsigned*)&hs_l[hoff], pl, __ATOMIC_RELAXED, __HIP_MEMORY_SCOPE_AGENT);
            if (t == NT_-1) {
                *(float2*)&hT[(size_t)eb*NH + hcol] = make_float2(hv[0], hv[1]);
                *(float2*)&cT[(size_t)eb*NH + hcol] = make_float2(creg[0], creg[1]);
            }

            // distributed-flag grid barrier
            asm volatile("s_waitcnt vmcnt(0)" ::: "memory");
            __syncthreads();
            if (tid == 0)
                __hip_atomic_store(&flags[bi*16], (unsigned)(t+1), __ATOMIC_RELAXED, __HIP_MEMORY_SCOPE_AGENT);
            // XW gather for t+1 (gated by xwcnt; done during the flag-wait window)
            if (t + 1 < NT_) {
                int guard = 0;
                while (__hip_atomic_load(&xwcnt[(t+1)*16], __ATOMIC_RELAXED, __HIP_MEMORY_SCOPE_AGENT) < 8u) {
                    __builtin_amdgcn_s_sleep(1);
                    if (++guard > (1<<22)) break;
                }
                #pragma unroll
                for (int g = 0; g < 4; g++)
                  #pragma unroll
                  for (int u = 0; u < 2; u++)
                    xw[g*2+u] = XW2[((size_t)(t+1)*NB + eb)*G4 + g*NH + bi*CPB + ec0 + u];
            }
            // every wave polls all 64 flags (64 lanes in parallel)
            {
                unsigned target = (unsigned)(t+1);
                int guard = 0;
                while (__hip_atomic_load(&flags[lane*16], __ATOMIC_RELAXED, __HIP_MEMORY_SCOPE_AGENT) < target) {
                    __builtin_amdgcn_s_sleep(1);
                    if (++guard > (1<<22)) break;
                }
            }
        }
    } else if (bid < RBLK + XWB) {
        // ================= gemm_xw role: one t, 4 waves x 64x64 n-tiles ===============
        // XW2[t][b][n] = X[b,t,:] . Wih[n,:] + b_ih[n] + b_hh[n]
        // A and B read from RAW FP32, split on the fly (bit-identical to pre-split)
        int e  = bid - RBLK;
        int t0 = e >> 3;                 // t ascending with blockIdx -> early steps first
        int n0 = ((e & 7) * 4 + w) * 64;
        f32x4 acc[4][4] = {};
        for (int kk = 0; kk < NI; kk += 32) {
            short8 ah[4], al[4], bh[4], bl[4];
            #pragma unroll
            for (int i = 0; i < 4; i++)
                ld8f2(input + ((size_t)(i*16+fr)*NT_ + t0)*NI + kk + fq*8, ah[i], al[i]);
            #pragma unroll
            for (int j = 0; j < 4; j++)
                ld8f2(W_ih + (size_t)(n0+j*16+fr)*NI + kk + fq*8, bh[j], bl[j]);
            #pragma unroll
            for (int i = 0; i < 4; i++)
                #pragma unroll
                for (int j = 0; j < 4; j++) {
                    acc[i][j] = __builtin_amdgcn_mfma_f32_16x16x32_bf16(ah[i], bh[j], acc[i][j], 0,0,0);
                    acc[i][j] = __builtin_amdgcn_mfma_f32_16x16x32_bf16(ah[i], bl[j], acc[i][j], 0,0,0);
                    acc[i][j] = __builtin_amdgcn_mfma_f32_16x16x32_bf16(al[i], bh[j], acc[i][j], 0,0,0);
                }
        }
        // write-through atomic stores (visible at L3 without kernel boundary)
        #pragma unroll
        for (int i = 0; i < 4; i++)
          #pragma unroll
          for (int j = 0; j < 4; j++)
            #pragma unroll
            for (int r = 0; r < 4; r++) {
                int b = i*16 + fq*4 + r;
                int n = n0 + j*16 + fr;
                float v = acc[i][j][r] + b_ih[n] + b_hh[n];
                union { float f; unsigned u; } cv; cv.f = v;
                __hip_atomic_store((unsigned*)&XW2[((size_t)t0*NB + b)*G4 + n], cv.u,
                                   __ATOMIC_RELAXED, __HIP_MEMORY_SCOPE_AGENT);
            }
        asm volatile("s_waitcnt vmcnt(0)" ::: "memory");   // data at coherence point
        __syncthreads();                                   // all 4 waves done
        if (tid == 0)
            __hip_atomic_fetch_add(&xwcnt[t0*16], 1u, __ATOMIC_RELAXED, __HIP_MEMORY_SCOPE_AGENT);
    } else if (bid < RBLK + XWB + TRB) {
        // ================= transpose_ctx role ========================================
        float (*tile)[65] = (float(*)[65])smem_raw;
        int tr = bid - (RBLK + XWB);
        int s0 = (tr & 7) * 64, h0 = ((tr >> 3) & 7) * 64, b = tr >> 6;
        int tx = tid & 63, ty = tid >> 6;
        for (int i = 0; i < 16; i++) {
            int s = i*4 + ty;
            tile[s][tx] = ctx[(size_t)(s0+s)*NB*NH + (size_t)b*NH + h0 + tx];
        }
        __syncthreads();
        for (int i = 0; i < 16; i++) {
            int h = i*4 + ty;
            ctxT[(size_t)b*NH*NS + (size_t)(h0+h)*NS + s0 + tx] = __float2bfloat16(tile[tx][h]);
        }
    } else {
        // ================= W_out conv_split role =====================================
        int wv = bid - (RBLK + XWB + TRB);
        for (int i = wv*256 + tid; i < NH*H2; i += WOB*256) {
            float x = W_out[i];
            __hip_bfloat16 h = __float2bfloat16(x);
            Wout_h[i] = h;
            Wout_l[i] = __float2bfloat16(x - __bfloat162float(h));
        }
    }
}

// ---------------- scores[b,t,s] = h[b,t,:] . ctx[s,b,:]  (A from hs hi/lo) ----------------
__global__ __launch_bounds__(256) void gemm_scores(const __hip_bfloat16* __restrict__ hs_h,
                                                   const __hip_bfloat16* __restrict__ hs_l,
                                                   const float* __restrict__ ctx,
                                                   float* __restrict__ scores) {
    int wid = blockIdx.x*4 + (threadIdx.x>>6);
    int lane = threadIdx.x & 63;
    int b  = wid >> 3;
    int n0 = (wid & 7) * 64;
    int fr = lane & 15, fq = lane >> 4;
    const __hip_bfloat16* Abh = hs_h + NB*NH + (size_t)b*NH;   // slot t+1, row stride NB*NH
    const __hip_bfloat16* Abl = hs_l + NB*NH + (size_t)b*NH;
    const float* Bb = ctx + (size_t)b*NH;
    f32x4 acc[4][4] = {};
    for (int kk = 0; kk < NH; kk += 32) {
        short8 ah[4], al[4], bh[4], bl[4];
        #pragma unroll
        for (int i = 0; i < 4; i++) {
            size_t off = (size_t)(i*16+fr)*NB*NH + kk + fq*8;
            ah[i] = ld8b(Abh + off);
            al[i] = ld8b(Abl + off);
        }
        #pragma unroll
        for (int j = 0; j < 4; j++) ld8f2(Bb + (size_t)(n0+j*16+fr)*NB*NH + kk + fq*8, bh[j], bl[j]);
        #pragma unroll
        for (int i = 0; i < 4; i++)
            #pragma unroll
            for (int j = 0; j < 4; j++) {
                acc[i][j] = __builtin_amdgcn_mfma_f32_16x16x32_bf16(ah[i], bh[j], acc[i][j], 0,0,0);
                acc[i][j] = __builtin_amdgcn_mfma_f32_16x16x32_bf16(ah[i], bl[j], acc[i][j], 0,0,0);
                acc[i][j] = __builtin_amdgcn_mfma_f32_16x16x32_bf16(al[i], bh[j], acc[i][j], 0,0,0);
            }
    }
    #pragma unroll
    for (int i = 0; i < 4; i++)
      #pragma unroll
      for (int j = 0; j < 4; j++)
        #pragma unroll
        for (int r = 0; r < 4; r++) {
            int t = i*16 + fq*4 + r;
            int s = n0 + j*16 + fr;
            scores[((size_t)b*NT_ + t)*NS + s] = acc[i][j][r];
        }
}

// ---------------- row softmax over S, output attn hi/lo bf16 ----------------
__global__ __launch_bounds__(256) void softmax_rows(const float* __restrict__ scores,
                                                    __hip_bfloat16* __restrict__ ah,
                                                    __hip_bfloat16* __restrict__ al) {
    int row = blockIdx.x*4 + (threadIdx.x>>6);
    int lane = threadIdx.x & 63;
    const float* r = scores + (size_t)row*NS;
    float v[8], mx = -1e30f;
    #pragma unroll
    for (int i = 0; i < 8; i++) { v[i] = r[lane + i*64]; mx = fmaxf(mx, v[i]); }
    #pragma unroll
    for (int off = 32; off; off >>= 1) mx = fmaxf(mx, __shfl_xor(mx, off));
    float sum = 0.f;
    #pragma unroll
    for (int i = 0; i < 8; i++) { v[i] = __expf(v[i]-mx); sum += v[i]; }
    #pragma unroll
    for (int off = 32; off; off >>= 1) sum += __shfl_xor(sum, off);
    float inv = 1.f/sum;
    #pragma unroll
    for (int i = 0; i < 8; i++) {
        float a = v[i]*inv;
        __hip_bfloat16 h = __float2bfloat16(a);
        ah[(size_t)row*NS + lane + i*64] = h;
        al[(size_t)row*NS + lane + i*64] = __float2bfloat16(a - __bfloat162float(h));
    }
}

// ---------------- Wc[b,t,h] = sum_s attn[b,t,s]*ctxT[b,h,s]  (fp32 out) ----------------
__global__ __launch_bounds__(256) void gemm_wc(const __hip_bfloat16* __restrict__ Ah,
                                               const __hip_bfloat16* __restrict__ Al,
                                               const __hip_bfloat16* __restrict__ ctxT,
                                               float* __restrict__ Wc) {
    int wid = blockIdx.x*4 + (threadIdx.x>>6);
    int lane = threadIdx.x & 63;
    int b  = wid >> 3;
    int n0 = (wid & 7) * 64;
    int fr = lane & 15, fq = lane >> 4;
    const __hip_bfloat16* Abh = Ah + (size_t)b*NT_*NS;
    const __hip_bfloat16* Abl = Al + (size_t)b*NT_*NS;
    const __hip_bfloat16* Bb  = ctxT + (size_t)b*NH*NS;
    f32x4 acc[4][4] = {};
    for (int kk = 0; kk < NS; kk += 32) {
        short8 ah[4], al[4], bb[4];
        #pragma unroll
        for (int i = 0; i < 4; i++) {
            ah[i] = ld8b(Abh + (size_t)(i*16+fr)*NS + kk + fq*8);
            al[i] = ld8b(Abl + (size_t)(i*16+fr)*NS + kk + fq*8);
        }
        #pragma unroll
        for (int j = 0; j < 4; j++) bb[j] = ld8b(Bb + (size_t)(n0+j*16+fr)*NS + kk + fq*8);
        #pragma unroll
        for (int i = 0; i < 4; i++)
            #pragma unroll
            for (int j = 0; j < 4; j++) {
                acc[i][j] = __builtin_amdgcn_mfma_f32_16x16x32_bf16(ah[i], bb[j], acc[i][j], 0,0,0);
                acc[i][j] = __builtin_amdgcn_mfma_f32_16x16x32_bf16(al[i], bb[j], acc[i][j], 0,0,0);
            }
    }
    #pragma unroll
    for (int i = 0; i < 4; i++)
      #pragma unroll
      for (int j = 0; j < 4; j++)
        #pragma unroll
        for (int r = 0; r < 4; r++) {
            int t = i*16 + fq*4 + r;
            int h = n0 + j*16 + fr;
            Wc[((size_t)b*NT_ + t)*NH + h] = acc[i][j][r];
        }
}

// ---------------- out = tanh([Wc|h] @ W_out^T)  (M=4096,N=512,K=1024) ----------------
__global__ __launch_bounds__(256) void gemm_out(const float* __restrict__ Wc,
                                                const __hip_bfloat16* __restrict__ hs_h,
                                                const __hip_bfloat16* __restrict__ hs_l,
                                                const __hip_bfloat16* __restrict__ Wh,
                                                const __hip_bfloat16* __restrict__ Wl,
                                                float* __restrict__ out) {
    int wid = blockIdx.x*4 + (threadIdx.x>>6);
    int lane = threadIdx.x & 63;
    int m0 = (wid >> 3) * 64;
    int n0 = (wid & 7) * 64;
    int fr = lane & 15, fq = lane >> 4;
    f32x4 acc[4][4] = {};
    // half 0: Wc (fp32, split on the fly), K cols [0,512)
    for (int kk = 0; kk < NH; kk += 32) {
        short8 ah[4], al[4], bh[4], bl[4];
        #pragma unroll
        for (int i = 0; i < 4; i++) ld8f2(Wc + (size_t)(m0+i*16+fr)*NH + kk + fq*8, ah[i], al[i]);
        #pragma unroll
        for (int j = 0; j < 4; j++) {
            bh[j] = ld8b(Wh + (size_t)(n0+j*16+fr)*H2 + kk + fq*8);
            bl[j] = ld8b(Wl + (size_t)(n0+j*16+fr)*H2 + kk + fq*8);
        }
        #pragma unroll
        for (int i = 0; i < 4; i++)
            #pragma unroll
            for (int j = 0; j < 4; j++) {
                acc[i][j] = __builtin_amdgcn_mfma_f32_16x16x32_bf16(ah[i], bh[j], acc[i][j], 0,0,0);
                acc[i][j] = __builtin_amdgcn_mfma_f32_16x16x32_bf16(ah[i], bl[j], acc[i][j], 0,0,0);
                acc[i][j] = __builtin_amdgcn_mfma_f32_16x16x32_bf16(al[i], bh[j], acc[i][j], 0,0,0);
            }
    }
    // half 1: h from hs time-series (bf16 hi/lo), K cols [512,1024)
    {
        const __hip_bfloat16* A2h = hs_h + NB*NH + (size_t)(m0>>6)*NH;  // row rloc=t -> slot t+1
        const __hip_bfloat16* A2l = hs_l + NB*NH + (size_t)(m0>>6)*NH;
        for (int kk = 0; kk < NH; kk += 32) {
            short8 ah[4], al[4], bh[4], bl[4];
            #pragma unroll
            for (int i = 0; i < 4; i++) {
                size_t off = (size_t)(i*16+fr)*NB*NH + kk + fq*8;
                ah[i] = ld8b(A2h + off);
                al[i] = ld8b(A2l + off);
            }
            #pragma unroll
            for (int j = 0; j < 4; j++) {
                bh[j] = ld8b(Wh + (size_t)(n0+j*16+fr)*H2 + NH + kk + fq*8);
                bl[j] = ld8b(Wl + (size_t)(n0+j*16+fr)*H2 + NH + kk + fq*8);
            }
            #pragma unroll
            for (int i = 0; i < 4; i++)
                #pragma unroll
                for (int j = 0; j < 4; j++) {
                    acc[i][j] = __builtin_amdgcn_mfma_f32_16x16x32_bf16(ah[i], bh[j], acc[i][j], 0,0,0);
                    acc[i][j] = __builtin_amdgcn_mfma_f32_16x16x32_bf16(ah[i], bl[j], acc[i][j], 0,0,0);
                    acc[i][j] = __builtin_amdgcn_mfma_f32_16x16x32_bf16(al[i], bh[j], acc[i][j], 0,0,0);
                }
        }
    }
    #pragma unroll
    for (int i = 0; i < 4; i++)
      #pragma unroll
      for (int j = 0; j < 4; j++)
        #pragma unroll
        for (int r = 0; r < 4; r++) {
            int m = m0 + i*16 + fq*4 + r;
            int n = n0 + j*16 + fr;
            out[(size_t)m*NH + n] = ftanh(acc[i][j][r]);
        }
}

// ---------------- workspace layout (authoritative offsets in kernel_launch) ----------------
// XW2 fp32 (T,B,4H) @0 (33.5MB); scores/attn overlay @0 after recurrence.
// hs @33.5MB; sync (flags+xwcnt, 8KB) @42.07MB; Wc @42.08MB; Wout_h/l @58.86MB;
// ctxT @60.96MB. (Xh/Xl + Wih/Whh splits no longer exist — conversions folded.)

extern "C" void kernel_launch(void* const* d_in, const int* in_sizes, int n_in,
                              void* d_out, int out_size, void* d_ws, size_t ws_size,
                              hipStream_t stream) {
    const float* input = (const float*)d_in[0];
    const float* h0    = (const float*)d_in[1];
    const float* c0    = (const float*)d_in[2];
    const float* ctx   = (const float*)d_in[3];
    const float* W_ih  = (const float*)d_in[4];
    const float* b_ih  = (const float*)d_in[5];
    const float* W_hh  = (const float*)d_in[6];
    const float* b_hh  = (const float*)d_in[7];
    const float* W_out = (const float*)d_in[8];
    float* out = (float*)d_out;

    const size_t OFF_XW     = 0;          // 33,554,432
    const size_t OFF_SCORES = 0;          //  8,388,608 (after recurrence)
    const size_t OFF_ATTN_H = 8388608;    //  4,194,304
    const size_t OFF_ATTN_L = 12582912;   //  4,194,304
    const size_t OFF_HS_H   = 33554432;   //  4,259,840
    const size_t OFF_HS_L   = 37814272;   //  4,259,840
    const size_t OFF_SYNC   = 42074112;   //      8,192 (flags 4KB + xwcnt 4KB)
    const size_t OFF_WC     = 42082304;   //  8,388,608
    const size_t OFF_WOUT_H = 58859520;   //  1,048,576
    const size_t OFF_WOUT_L = 59908096;   //  1,048,576
    const size_t OFF_CTXT   = 60956672;   // 33,554,432 -> end 94,511,104
    if (ws_size < 94511104u) return;  // fail loudly (d_out stays poisoned)

    char* ws = (char*)d_ws;
    float*          XW2    = (float*)(ws + OFF_XW);
    float*          scores = (float*)(ws + OFF_SCORES);
    __hip_bfloat16* attn_h = (__hip_bfloat16*)(ws + OFF_ATTN_H);
    __hip_bfloat16* attn_l = (__hip_bfloat16*)(ws + OFF_ATTN_L);
    __hip_bfloat16* hs_h   = (__hip_bfloat16*)(ws + OFF_HS_H);
    __hip_bfloat16* hs_l   = (__hip_bfloat16*)(ws + OFF_HS_L);
    unsigned*       sync   = (unsigned*)(ws + OFF_SYNC);
    unsigned*       flags  = sync;          // 64 x stride16 u32
    unsigned*       xwcnt  = sync + 1024;   // 64 x stride16 u32
    float*          Wc     = (float*)(ws + OFF_WC);
    __hip_bfloat16* Wout_h = (__hip_bfloat16*)(ws + OFF_WOUT_H);
    __hip_bfloat16* Wout_l = (__hip_bfloat16*)(ws + OFF_WOUT_L);
    __hip_bfloat16* ctxT   = (__hip_bfloat16*)(ws + OFF_CTXT);

    hseq0_init<<<128, 256, 0, stream>>>(h0, hs_h, hs_l, sync);

    float* hT = out + (size_t)BT*NH;
    float* cT = hT + NB*NH;
    lstm_mega<<<GRID_MEGA, 256, 0, stream>>>(c0, W_hh, input, W_ih,
                                             b_ih, b_hh, XW2, hs_h, hs_l, hT, cT,
                                             flags, xwcnt, ctx, ctxT, W_out, Wout_h, Wout_l);

    gemm_scores<<<128, 256, 0, stream>>>(hs_h, hs_l, ctx, scores);
    softmax_rows<<<1024, 256, 0, stream>>>(scores, attn_h, attn_l);
    gemm_wc<<<128, 256, 0, stream>>>(attn_h, attn_l, ctxT, Wc);
    gemm_out<<<128, 256, 0, stream>>>(Wc, hs_h, hs_l, Wout_h, Wout_l, out);
}